// Round 1
// baseline (1444.378 us; speedup 1.0000x reference)
//
#include <hip/hip_runtime.h>

// ---------------------------------------------------------------------------
// RGCN (basis decomposition, 2 layers) + mean-pool, f32 throughout.
//
// ws layout (bytes):
//   W1   [8][64][64] f32 @ 0          (131072)
//   W2   [8][64][16] f32 @ 131072     (32768)
//   agg1 [N][64] f32     @ 163840     (25,600,000)  -- becomes h (in-place relu)
//   agg2 [N][16] f32     @ 25,763,840 (6,400,000)
//   start[65] int        @ 32,163,840
// total ~32.2 MB
// ---------------------------------------------------------------------------

__device__ __forceinline__ float bcast(float v, int l) {
    return __uint_as_float(__builtin_amdgcn_readlane(__float_as_uint(v), l));
}

__global__ __launch_bounds__(256) void k_weights(
    const float* __restrict__ bases1, const float* __restrict__ coeff1,
    const float* __restrict__ bases2, const float* __restrict__ coeff2,
    float* __restrict__ W1, float* __restrict__ W2) {
    int r = blockIdx.x;
    float c1[8], c2[8];
#pragma unroll
    for (int b = 0; b < 8; ++b) { c1[b] = coeff1[r * 8 + b]; c2[b] = coeff2[r * 8 + b]; }
    for (int idx = threadIdx.x; idx < 64 * 64; idx += 256) {
        float s = 0.f;
#pragma unroll
        for (int b = 0; b < 8; ++b) s = fmaf(c1[b], bases1[b * 4096 + idx], s);
        W1[r * 4096 + idx] = s;
    }
    for (int idx = threadIdx.x; idx < 64 * 16; idx += 256) {
        float s = 0.f;
#pragma unroll
        for (int b = 0; b < 8; ++b) s = fmaf(c2[b], bases2[b * 1024 + idx], s);
        W2[r * 1024 + idx] = s;
    }
}

// agg1[n][j] = bias1[j] + sum_i x[n][i] * wself1[i][j]
__global__ __launch_bounds__(256) void k_lin1(
    const float* __restrict__ x, const float* __restrict__ wself,
    const float* __restrict__ bias, float* __restrict__ agg, int nNodes) {
    int lane = threadIdx.x & 63;
    int gw = (int)((blockIdx.x * blockDim.x + threadIdx.x) >> 6);
    int nW = (int)((gridDim.x * blockDim.x) >> 6);
    float w[64];
#pragma unroll
    for (int i = 0; i < 64; ++i) w[i] = wself[i * 64 + lane];
    float bj = bias[lane];
    for (int n = gw; n < nNodes; n += nW) {
        float xv = x[n * 64 + lane];
        float a0 = 0.f, a1 = 0.f, a2 = 0.f, a3 = 0.f;
#pragma unroll
        for (int i = 0; i < 64; i += 4) {
            a0 = fmaf(bcast(xv, i + 0), w[i + 0], a0);
            a1 = fmaf(bcast(xv, i + 1), w[i + 1], a1);
            a2 = fmaf(bcast(xv, i + 2), w[i + 2], a2);
            a3 = fmaf(bcast(xv, i + 3), w[i + 3], a3);
        }
        agg[n * 64 + lane] = bj + ((a0 + a1) + (a2 + a3));
    }
}

// in-place: h = relu(agg1) written back to agg1; agg2[n][j] = bias2[j] + h[n]@wself2
__global__ __launch_bounds__(256) void k_lin2(
    float* __restrict__ agg1, const float* __restrict__ wself,
    const float* __restrict__ bias, float* __restrict__ agg2, int nNodes) {
    int lane = threadIdx.x & 63;
    int j = lane & 15;
    int gw = (int)((blockIdx.x * blockDim.x + threadIdx.x) >> 6);
    int nW = (int)((gridDim.x * blockDim.x) >> 6);
    float w[64];
#pragma unroll
    for (int i = 0; i < 64; ++i) w[i] = wself[i * 16 + j];
    float bj = bias[j];
    for (int n = gw; n < nNodes; n += nW) {
        float hv = fmaxf(agg1[n * 64 + lane], 0.f);
        agg1[n * 64 + lane] = hv;  // h stored in place
        float a0 = 0.f, a1 = 0.f, a2 = 0.f, a3 = 0.f;
#pragma unroll
        for (int i = 0; i < 64; i += 4) {
            a0 = fmaf(bcast(hv, i + 0), w[i + 0], a0);
            a1 = fmaf(bcast(hv, i + 1), w[i + 1], a1);
            a2 = fmaf(bcast(hv, i + 2), w[i + 2], a2);
            a3 = fmaf(bcast(hv, i + 3), w[i + 3], a3);
        }
        if (lane < 16) agg2[n * 16 + lane] = bj + ((a0 + a1) + (a2 + a3));
    }
}

// Edge messages for one relation (blockIdx.z): y = W_r^T-applied GEMV, atomic scatter.
template <int OW>
__global__ __launch_bounds__(256) void k_edge(
    const float* __restrict__ xin, const int* __restrict__ src,
    const int* __restrict__ dst, const int* __restrict__ et,
    const float* __restrict__ W, float* __restrict__ agg, int nE) {
    const int lane = threadIdx.x & 63;
    const int r = blockIdx.z;
    const int wid = (int)(threadIdx.x >> 6);
    const int EPB = 2048, EPW = 512;
    int e0 = blockIdx.x * EPB + wid * EPW;
    int e1 = min(e0 + EPW, nE);
    const float* Wr = W + r * 64 * OW;
    int j = (OW == 64) ? lane : (lane & (OW - 1));
    float w[64];
#pragma unroll
    for (int i = 0; i < 64; ++i) w[i] = Wr[i * OW + j];
    for (int e = e0; e < e1; ++e) {
        if (et[e] != r) continue;  // wave-uniform
        int s = src[e], d = dst[e];
        float xv = xin[s * 64 + lane];
        float a0 = 0.f, a1 = 0.f, a2 = 0.f, a3 = 0.f;
#pragma unroll
        for (int i = 0; i < 64; i += 4) {
            a0 = fmaf(bcast(xv, i + 0), w[i + 0], a0);
            a1 = fmaf(bcast(xv, i + 1), w[i + 1], a1);
            a2 = fmaf(bcast(xv, i + 2), w[i + 2], a2);
            a3 = fmaf(bcast(xv, i + 3), w[i + 3], a3);
        }
        float acc = (a0 + a1) + (a2 + a3);
        if (lane < OW) atomicAdd(&agg[d * OW + lane], acc);
    }
}

__global__ void k_bounds(const int* __restrict__ gid, int* __restrict__ start, int nNodes) {
    int t = blockIdx.x * blockDim.x + threadIdx.x;
    if (t > 64) return;
    int lo = 0, hi = nNodes;
    while (lo < hi) {
        int mid = (lo + hi) >> 1;
        if (gid[mid] < t) lo = mid + 1; else hi = mid;
    }
    start[t] = lo;
}

__global__ __launch_bounds__(256) void k_pool(
    const float* __restrict__ agg2, const int* __restrict__ start,
    float* __restrict__ out) {
    __shared__ float sm[256];
    int g = blockIdx.x;
    int t = threadIdx.x;
    int c = t & 15, idx = t >> 4;
    int s0 = start[g], s1 = start[g + 1];
    float acc = 0.f;
    for (int n = s0 + idx; n < s1; n += 16) acc += fmaxf(agg2[n * 16 + c], 0.f);
    sm[t] = acc;
    __syncthreads();
#pragma unroll
    for (int off = 128; off >= 16; off >>= 1) {
        if (t < off) sm[t] += sm[t + off];
        __syncthreads();
    }
    if (t < 16) {
        float cnt = (float)(s1 - s0);
        out[g * 16 + t] = sm[t] / fmaxf(cnt, 1.f);
    }
}

extern "C" void kernel_launch(void* const* d_in, const int* in_sizes, int n_in,
                              void* d_out, int out_size, void* d_ws, size_t ws_size,
                              hipStream_t stream) {
    const float* x      = (const float*)d_in[0];
    const int*   src    = (const int*)d_in[1];
    const int*   dst    = (const int*)d_in[2];
    const int*   et     = (const int*)d_in[3];
    const int*   gid    = (const int*)d_in[4];
    const float* bases1 = (const float*)d_in[5];
    const float* coeff1 = (const float*)d_in[6];
    const float* wself1 = (const float*)d_in[7];
    const float* bias1  = (const float*)d_in[8];
    const float* bases2 = (const float*)d_in[9];
    const float* coeff2 = (const float*)d_in[10];
    const float* wself2 = (const float*)d_in[11];
    const float* bias2  = (const float*)d_in[12];
    float* out = (float*)d_out;

    int nNodes = in_sizes[0] / 64;
    int nE = in_sizes[1];

    char* ws = (char*)d_ws;
    float* W1   = (float*)(ws);
    float* W2   = (float*)(ws + 131072);
    float* agg1 = (float*)(ws + 163840);
    float* agg2 = (float*)(ws + 25763840);
    int*   start = (int*)(ws + 32163840);

    hipLaunchKernelGGL(k_weights, dim3(8), dim3(256), 0, stream,
                       bases1, coeff1, bases2, coeff2, W1, W2);
    hipLaunchKernelGGL(k_lin1, dim3(512), dim3(256), 0, stream,
                       x, wself1, bias1, agg1, nNodes);
    int eb = (nE + 2047) / 2048;
    hipLaunchKernelGGL((k_edge<64>), dim3(eb, 1, 8), dim3(256), 0, stream,
                       x, src, dst, et, W1, agg1, nE);
    hipLaunchKernelGGL(k_lin2, dim3(512), dim3(256), 0, stream,
                       agg1, wself2, bias2, agg2, nNodes);
    hipLaunchKernelGGL((k_edge<16>), dim3(eb, 1, 8), dim3(256), 0, stream,
                       agg1, src, dst, et, W2, agg2, nE);
    hipLaunchKernelGGL(k_bounds, dim3(1), dim3(128), 0, stream, gid, start, nNodes);
    hipLaunchKernelGGL(k_pool, dim3(64), dim3(256), 0, stream, agg2, start, out);
}